// Round 19
// baseline (46.537 us; speedup 1.0000x reference)
//
#include <hip/hip_runtime.h>
#include <math.h>

constexpr int Bn = 256;
constexpr int Tn = 4096;
constexpr int Sn = 32;
constexpr int NE = 16;            // sixteenths per row
constexpr int EL = Tn / NE;       // 256 t per block
// K1: 256 threads, 8 tc-groups x 32 states, 32 t/thread
constexpr int NT1 = 256;
constexpr int TCN = 8;
constexpr int TL = EL / TCN;      // 32
constexpr int CL = 16;
constexpr int CPT = TL / CL;      // 2
// K2: 128 threads, 8 t-groups x 16 state-pairs, 32 t x 2 states/thread (R18 per-thread structure)
constexpr int NT2 = 128;
constexpr int NG  = 8;            // t-groups per block
constexpr int GW  = EL / NG;      // 32 t per group
constexpr int CL2 = 8;
constexpr int CPT2 = GW / CL2;    // 4
constexpr float HALF_LN2PI = 0.918938533204672742f;
constexpr float SAT = -3.0e38f;   // final clamp (ref hits -inf; only NaN fails)
constexpr float PCLAMP = 1.0e38f; // keep power multipliers finite (never 0*inf)

constexpr size_t OFF_LF = 0;                      // ws: [Bn][NE][Sn] fwd sixteenth aggregates
constexpr size_t OFF_LB = (size_t)Bn * NE * Sn;   // ws: [Bn][NE][Sn] bwd sixteenth aggregates

// NaN-safety invariant (per state s): all per-step g-terms < 0 => f/b <= 0; +inf
// unreachable. w>1 states may reach -inf (their multipliers >=1, clamped <=1e38:
// never 0*inf). w<1 states stay finite when multipliers underflow to 0.
// exp(v<=0) <= 1. Clamp once at the store => output finite, never NaN.

#define DPP_ADD(x, ctrl) \
    ((x) + __int_as_float(__builtin_amdgcn_update_dpp(0, __float_as_int(x), (ctrl), 0xF, 0xF, false)))

// K1: block (b, sixteenth) — per-thread 32-step chains -> 3-round KS -> aggregates.
__global__ __launch_bounds__(NT1, 8) void hmm_agg_kernel(
    const float* __restrict__ obvs, const float* __restrict__ ln_pi,
    const float* __restrict__ trans_w, const float* __restrict__ trans_b,
    const float* __restrict__ mu, const float* __restrict__ log_sigma,
    float* __restrict__ ws)
{
    __shared__ __align__(16) float s_obvs[EL];   // 1 KB
    __shared__ float s_PF[TCN][Sn];
    __shared__ float s_ZB[TCN][Sn];

    const int be  = blockIdx.x;                  // b*NE + e
    const int b   = be >> 4;
    const int e   = be & (NE - 1);
    const int tid = threadIdx.x;
    const int s   = tid & 31;
    const int tc  = tid >> 5;                    // 0..7
    const int t0  = tc * TL;

    if (tid < EL / 4)
        ((float4*)s_obvs)[tid] = ((const float4*)(obvs + (size_t)b * Tn + (size_t)e * EL))[tid];

    const float w  = trans_w[s];
    const float tb = trans_b[s];
    const float pi = ln_pi[s];
    const float m  = mu[s];
    const float ls = log_sigma[s];
    const float inv = __expf(-ls);
    const float cqa  = -0.5f * inv * inv;
    const float cqb  = m * inv * inv;
    const float cqcb = -ls - HALF_LN2PI - 0.5f * m * m * inv * inv + tb;
    const float tbb  = tb - w * tb;
    float w16; { float w2 = w * w, w4 = w2 * w2; float w8 = w4 * w4; w16 = w8 * w8; }
    const float W32 = fminf(w16 * w16, PCLAMP);
    const bool th0  = (e == 0) && (tc == 0);

    __syncthreads();

#define EMIT(xv) fmaf(fmaf(cqa, (xv), cqb), (xv), cqcb)

    float lbs[CPT];
    float AF = 0.f;
#pragma unroll
    for (int i = 0; i < CPT; ++i) {
        const float4* q4 = (const float4*)(s_obvs + t0 + i * CL);
        float4 v0 = q4[0], v1 = q4[1], v2 = q4[2], v3 = q4[3];
        float x[CL] = {v0.x, v0.y, v0.z, v0.w, v1.x, v1.y, v1.z, v1.w,
                       v2.x, v2.y, v2.z, v2.w, v3.x, v3.y, v3.z, v3.w};
#pragma unroll
        for (int j = 0; j < CL; ++j) {
            float g = EMIT(x[j]);
            if (th0 && i == 0 && j == 0) g += pi - tb;
            AF = fmaf(w, AF, g);
        }
        float l = 0.f;
#pragma unroll
        for (int j = CL - 2; j >= -1; --j)
            l = fmaf(w, l + EMIT(x[j + 1]), tbb);
        lbs[i] = l;
    }
    const float ZT = fmaf(w16, lbs[1], lbs[0]);

    s_PF[tc][s] = AF;
    s_ZB[tc][s] = ZT;
    __syncthreads();

    {
        float Wd = W32;
#pragma unroll
        for (int r = 0; r < 3; ++r) {
            const int d = 1 << r;
            float tF = (tc >= d)      ? s_PF[tc - d][s] : 0.f;
            float tB = (tc + d < TCN) ? s_ZB[tc + d][s] : 0.f;
            __syncthreads();
            if (tc >= d)      s_PF[tc][s] = fmaf(Wd, tF, s_PF[tc][s]);
            if (tc + d < TCN) s_ZB[tc][s] = fmaf(Wd, tB, s_ZB[tc][s]);
            Wd = fminf(Wd * Wd, PCLAMP);
            __syncthreads();
        }
    }

    if (tc == 7) ws[OFF_LF + (size_t)be * Sn + s] = s_PF[TCN - 1][s];
    if (tc == 0) ws[OFF_LB + (size_t)be * Sn + s] = s_ZB[0][s];
#undef EMIT
}

// K2: 128-thread block per (b, sixteenth); 2 states/thread (R18 per-thread structure).
__global__ __launch_bounds__(NT2) void hmm_main_kernel(
    const float* __restrict__ obvs, const float* __restrict__ ln_pi,
    const float* __restrict__ trans_w, const float* __restrict__ trans_b,
    const float* __restrict__ mu, const float* __restrict__ log_sigma,
    float* __restrict__ out, const float* __restrict__ ws)
{
    __shared__ __align__(16) float s_obvs[EL];   // 1 KB
    __shared__ __align__(8) float s_PF[NG][Sn];  // 1 KB
    __shared__ __align__(8) float s_ZB[NG][Sn];  // 1 KB

    const int be  = blockIdx.x;
    const int b   = be >> 4;
    const int e   = be & (NE - 1);
    const int tid = threadIdx.x;
    const int sp  = tid & 15;        // state pair
    const int g   = tid >> 4;        // t-group 0..7
    const int s0  = 2 * sp;
    const int t0  = g * GW;

    if (tid < EL / 4)
        ((float4*)s_obvs)[tid] = ((const float4*)(obvs + (size_t)b * Tn + (size_t)e * EL))[tid];

    const float2 wv  = *(const float2*)&trans_w[s0];
    const float2 tbv = *(const float2*)&trans_b[s0];
    const float2 piv = *(const float2*)&ln_pi[s0];
    const float2 muv = *(const float2*)&mu[s0];
    const float2 lsv = *(const float2*)&log_sigma[s0];
    const float inv0 = __expf(-lsv.x), inv1 = __expf(-lsv.y);
    const float cqa0 = -0.5f * inv0 * inv0,          cqa1 = -0.5f * inv1 * inv1;
    const float cqb0 = muv.x * inv0 * inv0,          cqb1 = muv.y * inv1 * inv1;
    const float cqc0 = -lsv.x - HALF_LN2PI - 0.5f * muv.x * muv.x * inv0 * inv0 + tbv.x;
    const float cqc1 = -lsv.y - HALF_LN2PI - 0.5f * muv.y * muv.y * inv1 * inv1 + tbv.y;
    const float tbb0 = tbv.x - wv.x * tbv.x,         tbb1 = tbv.y - wv.y * tbv.y;
    float w8_0, w8_1;
    { float a2 = wv.x * wv.x, a4 = a2 * a2; w8_0 = a4 * a4;
      float b2 = wv.y * wv.y, b4 = b2 * b2; w8_1 = b4 * b4; }
    const float w16_0 = fminf(w8_0 * w8_0, PCLAMP), w16_1 = fminf(w8_1 * w8_1, PCLAMP);
    const float w24_0 = fminf(w16_0 * w8_0, PCLAMP), w24_1 = fminf(w16_1 * w8_1, PCLAMP);
    const float W32_0 = fminf(w16_0 * w16_0, PCLAMP), W32_1 = fminf(w16_1 * w16_1, PCLAMP);
    const float l2w0 = log2f(wv.x), l2w1 = log2f(wv.y);
    const float WEL0 = fminf(exp2f(l2w0 * (float)EL), PCLAMP);   // w^256
    const float WEL1 = fminf(exp2f(l2w1 * (float)EL), PCLAMP);
    const float pY0 = fminf(exp2f(l2w0 * (float)(GW * g)), PCLAMP);
    const float pY1 = fminf(exp2f(l2w1 * (float)(GW * g)), PCLAMP);
    const float pX0 = fminf(exp2f(l2w0 * (float)(GW * (NG - 1 - g))), PCLAMP);
    const float pX1 = fminf(exp2f(l2w1 * (float)(GW * (NG - 1 - g))), PCLAMP);
    const bool th0 = (e == 0) && (g == 0);

    __syncthreads();

#define EMIT0(xv) fmaf(fmaf(cqa0, (xv), cqb0), (xv), cqc0)
#define EMIT1(xv) fmaf(fmaf(cqa1, (xv), cqb1), (xv), cqc1)

    // ---- Phase A: per-chunk zero-carry scans, both states ----
    float lbs0[CPT2], lbs1[CPT2];
    float AF0 = 0.f, AF1 = 0.f;
#pragma unroll
    for (int i = 0; i < CPT2; ++i) {
        const float4* q4 = (const float4*)(s_obvs + t0 + i * CL2);
        float4 va = q4[0], vb = q4[1];
        float x[CL2] = {va.x, va.y, va.z, va.w, vb.x, vb.y, vb.z, vb.w};
        float e0[CL2];
#pragma unroll
        for (int j = 0; j < CL2; ++j) { e0[j] = EMIT0(x[j]); x[j] = EMIT1(x[j]); }
        if (th0 && i == 0) { e0[0] += piv.x - tbv.x; x[0] += piv.y - tbv.y; }
#pragma unroll
        for (int j = 0; j < CL2; ++j) {
            AF0 = fmaf(wv.x, AF0, e0[j]);
            AF1 = fmaf(wv.y, AF1, x[j]);
        }
        float l0 = 0.f, l1 = 0.f;
#pragma unroll
        for (int j = CL2 - 2; j >= -1; --j) {
            l0 = fmaf(wv.x, l0 + e0[j + 1], tbb0);
            l1 = fmaf(wv.y, l1 + x[j + 1], tbb1);
        }
        lbs0[i] = l0; lbs1[i] = l1;
    }
    const float Z3_0 = lbs0[3], Z3_1 = lbs1[3];
    const float Z2_0 = fmaf(w8_0, Z3_0, lbs0[2]), Z2_1 = fmaf(w8_1, Z3_1, lbs1[2]);
    const float Z1_0 = fmaf(w8_0, Z2_0, lbs0[1]), Z1_1 = fmaf(w8_1, Z2_1, lbs1[1]);
    const float ZT0  = fmaf(w8_0, Z1_0, lbs0[0]), ZT1  = fmaf(w8_1, Z1_1, lbs1[0]);

    *(float2*)&s_PF[g][s0] = make_float2(AF0, AF1);
    *(float2*)&s_ZB[g][s0] = make_float2(ZT0, ZT1);
    __syncthreads();

    // ---- Phase B: 3-round Kogge-Stone over 8 group aggregates ----
    {
        float Wd0 = W32_0, Wd1 = W32_1;
#pragma unroll
        for (int r = 0; r < 3; ++r) {
            const int d = 1 << r;
            float2 tF = (g >= d)     ? *(const float2*)&s_PF[g - d][s0] : make_float2(0.f, 0.f);
            float2 tB = (g + d < NG) ? *(const float2*)&s_ZB[g + d][s0] : make_float2(0.f, 0.f);
            __syncthreads();
            if (g >= d) {
                s_PF[g][s0]     = fmaf(Wd0, tF.x, s_PF[g][s0]);
                s_PF[g][s0 + 1] = fmaf(Wd1, tF.y, s_PF[g][s0 + 1]);
            }
            if (g + d < NG) {
                s_ZB[g][s0]     = fmaf(Wd0, tB.x, s_ZB[g][s0]);
                s_ZB[g][s0 + 1] = fmaf(Wd1, tB.y, s_ZB[g][s0 + 1]);
            }
            Wd0 = fminf(Wd0 * Wd0, PCLAMP);
            Wd1 = fminf(Wd1 * Wd1, PCLAMP);
            __syncthreads();
        }
    }

    // ---- cross-sixteenth carries from ws ----
    float Y0 = 0.f, Y1 = 0.f;
#pragma unroll
    for (int qq = 0; qq < NE - 1; ++qq)
        if (qq < e) {
            float2 L = *(const float2*)&ws[OFF_LF + (size_t)(b * NE + qq) * Sn + s0];
            Y0 = fmaf(WEL0, Y0, L.x);
            Y1 = fmaf(WEL1, Y1, L.y);
        }
    float xT = obvs[(size_t)b * Tn + Tn - 1];
    float X0 = EMIT0(xT) + (piv.x - tbv.x);
    float X1 = EMIT1(xT) + (piv.y - tbv.y);
#pragma unroll
    for (int qq = NE - 1; qq > 0; --qq)
        if (qq > e) {
            float2 L = *(const float2*)&ws[OFF_LB + (size_t)(b * NE + qq) * Sn + s0];
            X0 = fmaf(WEL0, X0, L.x);
            X1 = fmaf(WEL1, X1, L.y);
        }

    // ---- thread carries ----
    float2 Pp = (g > 0)      ? *(const float2*)&s_PF[g - 1][s0] : make_float2(0.f, 0.f);
    float2 Zn = (g < NG - 1) ? *(const float2*)&s_ZB[g + 1][s0] : make_float2(0.f, 0.f);
    float f0 = fmaf(pY0, Y0, Pp.x);
    float f1 = fmaf(pY1, Y1, Pp.y);
    const float Xth0 = fmaf(pX0, X0, Zn.x);
    const float Xth1 = fmaf(pX1, X1, Zn.y);
    float R0[CPT2], R1[CPT2];
    R0[3] = Xth0;                    R1[3] = Xth1;
    R0[2] = fmaf(w8_0,  Xth0, Z3_0); R1[2] = fmaf(w8_1,  Xth1, Z3_1);
    R0[1] = fmaf(w16_0, Xth0, Z2_0); R1[1] = fmaf(w16_1, Xth1, Z2_1);
    R0[0] = fmaf(w24_0, Xth0, Z1_0); R1[0] = fmaf(w24_1, Xth1, Z1_1);

    const size_t rowbase = (size_t)b * Tn + (size_t)e * EL;
    float* outp = out + ((rowbase + t0) << 5) + s0;

    // ---- Phase C: dual f-chains + dual bwd fills + shared LSE + float2 stores ----
#pragma unroll
    for (int i = 0; i < CPT2; ++i) {
        const float4* q4 = (const float4*)(s_obvs + t0 + i * CL2);
        float4 va = q4[0], vb = q4[1];
        float x[CL2] = {va.x, va.y, va.z, va.w, vb.x, vb.y, vb.z, vb.w};
        float e0[CL2];
#pragma unroll
        for (int j = 0; j < CL2; ++j) { e0[j] = EMIT0(x[j]); x[j] = EMIT1(x[j]); }
        if (th0 && i == 0) { e0[0] += piv.x - tbv.x; x[0] += piv.y - tbv.y; }

        float b0[CL2], b1[CL2];
        b0[CL2 - 1] = R0[i]; b1[CL2 - 1] = R1[i];
#pragma unroll
        for (int j = CL2 - 2; j >= 0; --j) {
            b0[j] = fmaf(wv.x, b0[j + 1] + e0[j + 1], tbb0);
            b1[j] = fmaf(wv.y, b1[j + 1] + x[j + 1], tbb1);
        }

#pragma unroll
        for (int j = 0; j < CL2; ++j) {
            f0 = fmaf(wv.x, f0, e0[j]);
            f1 = fmaf(wv.y, f1, x[j]);
            float v0 = f0 + b0[j];
            float v1 = f1 + b1[j];
            float sum = __expf(v0) + __expf(v1);   // v <= 0
            sum = DPP_ADD(sum, 0xB1);              // quad_perm xor1
            sum = DPP_ADD(sum, 0x4E);              // quad_perm xor2
            sum = DPP_ADD(sum, 0x141);             // row_half_mirror
            sum = DPP_ADD(sum, 0x128);             // row_ror:8
            sum = fmaxf(sum, 1.0e-35f);
            float lse = __logf(sum);
            float2 r = make_float2(fmaxf(v0 - lse, SAT), fmaxf(v1 - lse, SAT));
            *(float2*)(outp + ((size_t)(i * CL2 + j) << 5)) = r;
        }
    }
#undef EMIT0
#undef EMIT1
}

extern "C" void kernel_launch(void* const* d_in, const int* in_sizes, int n_in,
                              void* d_out, int out_size, void* d_ws, size_t ws_size,
                              hipStream_t stream)
{
    const float* obvs      = (const float*)d_in[0];
    const float* ln_pi     = (const float*)d_in[1];
    const float* trans_w   = (const float*)d_in[2];
    const float* trans_b   = (const float*)d_in[3];
    const float* mu        = (const float*)d_in[4];
    const float* log_sigma = (const float*)d_in[5];
    float* out = (float*)d_out;
    float* wsf = (float*)d_ws;    // 512 KB used

    hipLaunchKernelGGL(hmm_agg_kernel, dim3(Bn * NE), dim3(NT1), 0, stream,
                       obvs, ln_pi, trans_w, trans_b, mu, log_sigma, wsf);
    hipLaunchKernelGGL(hmm_main_kernel, dim3(Bn * NE), dim3(NT2), 0, stream,
                       obvs, ln_pi, trans_w, trans_b, mu, log_sigma, out, wsf);
}

// Round 20
// 43.268 us; speedup vs baseline: 1.0756x; 1.0756x over previous
//
#include <hip/hip_runtime.h>
#include <math.h>

constexpr int Bn = 256;
constexpr int Tn = 4096;
constexpr int Sn = 32;
constexpr int NE = 8;             // eighths per row
constexpr int EL = Tn / NE;       // 512
constexpr int NT2 = 256;
// K1 decomposition (R14-proven): 8 tc-groups x 32 states, 64 t/thread
constexpr int TCN = 8;
constexpr int TL = 64;
constexpr int CL = 16;
constexpr int CPT = 4;
// K2 decomposition (R18-proven best): 16 t-groups x 16 state-pairs, 32 t x 2 states/thread
constexpr int NG  = 16;           // t-groups per block
constexpr int GW  = EL / NG;      // 32 t per group
constexpr int CL2 = 8;            // chunk
constexpr int CPT2 = GW / CL2;    // 4
constexpr float HALF_LN2PI = 0.918938533204672742f;
constexpr float SAT = -3.0e38f;   // final clamp (ref hits -inf; only NaN fails)
constexpr float PCLAMP = 1.0e38f; // keep power multipliers finite (never 0*inf)

constexpr size_t OFF_LF = 0;                      // ws: [Bn][NE][Sn] fwd eighth aggregates
constexpr size_t OFF_LB = (size_t)Bn * NE * Sn;   // ws: [Bn][NE][Sn] bwd eighth aggregates

// NaN-safety invariant (per state s): all per-step g-terms < 0 => f/b <= 0; +inf
// unreachable. w>1 states may reach -inf (their multipliers >=1, clamped <=1e38:
// never 0*inf). w<1 states stay finite when multipliers underflow to 0.
// exp(v<=0) <= 1. Clamp once at the store => output finite, never NaN.

#define DPP_ADD(x, ctrl) \
    ((x) + __int_as_float(__builtin_amdgcn_update_dpp(0, __float_as_int(x), (ctrl), 0xF, 0xF, false)))
// 16-lane all-sum, all on VALU: quad xor1 (0xB1), quad xor2 (0x4E),
// row_half_mirror (0x141), row_ror:8 (0x128)

// K1: block (b, eighth) — R14-proven, unchanged (~2-3 us).
__global__ __launch_bounds__(NT2, 8) void hmm_agg_kernel(
    const float* __restrict__ obvs, const float* __restrict__ ln_pi,
    const float* __restrict__ trans_w, const float* __restrict__ trans_b,
    const float* __restrict__ mu, const float* __restrict__ log_sigma,
    float* __restrict__ ws)
{
    __shared__ __align__(16) float s_obvs[EL];
    __shared__ float s_PF[TCN][Sn];
    __shared__ float s_ZB[TCN][Sn];

    const int be  = blockIdx.x;
    const int b   = be >> 3;
    const int e   = be & (NE - 1);
    const int tid = threadIdx.x;
    const int s   = tid & 31;
    const int tc  = tid >> 5;
    const int t0  = tc * TL;

    if (tid < EL / 4)
        ((float4*)s_obvs)[tid] = ((const float4*)(obvs + (size_t)b * Tn + (size_t)e * EL))[tid];

    const float w  = trans_w[s];
    const float tb = trans_b[s];
    const float pi = ln_pi[s];
    const float m  = mu[s];
    const float ls = log_sigma[s];
    const float inv = __expf(-ls);
    const float cqa  = -0.5f * inv * inv;
    const float cqb  = m * inv * inv;
    const float cqcb = -ls - HALF_LN2PI - 0.5f * m * m * inv * inv + tb;
    const float tbb  = tb - w * tb;
    float w16; { float w2 = w * w, w4 = w2 * w2; float w8 = w4 * w4; w16 = w8 * w8; }
    const float w32 = fminf(w16 * w16, PCLAMP);
    const float W64 = fminf(w32 * w32, PCLAMP);
    const bool th0  = (e == 0) && (tc == 0);

    __syncthreads();

#define EMIT(xv) fmaf(fmaf(cqa, (xv), cqb), (xv), cqcb)

    float lbs[CPT];
    float AF = 0.f;
#pragma unroll
    for (int i = 0; i < CPT; ++i) {
        const float4* q4 = (const float4*)(s_obvs + t0 + i * CL);
        float4 v0 = q4[0], v1 = q4[1], v2 = q4[2], v3 = q4[3];
        float x[CL] = {v0.x, v0.y, v0.z, v0.w, v1.x, v1.y, v1.z, v1.w,
                       v2.x, v2.y, v2.z, v2.w, v3.x, v3.y, v3.z, v3.w};
#pragma unroll
        for (int j = 0; j < CL; ++j) {
            float g = EMIT(x[j]);
            if (th0 && i == 0 && j == 0) g += pi - tb;
            AF = fmaf(w, AF, g);
        }
        float l = 0.f;
#pragma unroll
        for (int j = CL - 2; j >= -1; --j)
            l = fmaf(w, l + EMIT(x[j + 1]), tbb);
        lbs[i] = l;
    }
    const float Z3 = lbs[3];
    const float Z2 = fmaf(w16, Z3, lbs[2]);
    const float Z1 = fmaf(w16, Z2, lbs[1]);
    const float ZT = fmaf(w16, Z1, lbs[0]);

    s_PF[tc][s] = AF;
    s_ZB[tc][s] = ZT;
    __syncthreads();

    {
        float Wd = W64;
#pragma unroll
        for (int r = 0; r < 3; ++r) {
            const int d = 1 << r;
            float tF = (tc >= d)      ? s_PF[tc - d][s] : 0.f;
            float tB = (tc + d < TCN) ? s_ZB[tc + d][s] : 0.f;
            __syncthreads();
            if (tc >= d)      s_PF[tc][s] = fmaf(Wd, tF, s_PF[tc][s]);
            if (tc + d < TCN) s_ZB[tc][s] = fmaf(Wd, tB, s_ZB[tc][s]);
            Wd = fminf(Wd * Wd, PCLAMP);
            __syncthreads();
        }
    }

    if (tc == 7) ws[OFF_LF + (size_t)be * Sn + s] = s_PF[TCN - 1][s];
    if (tc == 0) ws[OFF_LB + (size_t)be * Sn + s] = s_ZB[0][s];
#undef EMIT
}

// K2: 2 states per thread (R18-proven best). sp = tid&15 -> states {2sp, 2sp+1};
// g = tid>>4 -> 32-t window. LSE reduce = 1 in-thread add + 4 DPP row ops.
__global__ __launch_bounds__(NT2) void hmm_main_kernel(
    const float* __restrict__ obvs, const float* __restrict__ ln_pi,
    const float* __restrict__ trans_w, const float* __restrict__ trans_b,
    const float* __restrict__ mu, const float* __restrict__ log_sigma,
    float* __restrict__ out, const float* __restrict__ ws)
{
    __shared__ __align__(16) float s_obvs[EL];   // 2 KB
    __shared__ __align__(8) float s_PF[NG][Sn];  // 2 KB
    __shared__ __align__(8) float s_ZB[NG][Sn];  // 2 KB

    const int be  = blockIdx.x;
    const int b   = be >> 3;
    const int e   = be & (NE - 1);
    const int tid = threadIdx.x;
    const int sp  = tid & 15;        // state pair
    const int g   = tid >> 4;        // t-group 0..15
    const int s0  = 2 * sp;
    const int t0  = g * GW;

    if (tid < EL / 4)
        ((float4*)s_obvs)[tid] = ((const float4*)(obvs + (size_t)b * Tn + (size_t)e * EL))[tid];

    const float2 wv  = *(const float2*)&trans_w[s0];
    const float2 tbv = *(const float2*)&trans_b[s0];
    const float2 piv = *(const float2*)&ln_pi[s0];
    const float2 muv = *(const float2*)&mu[s0];
    const float2 lsv = *(const float2*)&log_sigma[s0];
    const float inv0 = __expf(-lsv.x), inv1 = __expf(-lsv.y);
    const float cqa0 = -0.5f * inv0 * inv0,          cqa1 = -0.5f * inv1 * inv1;
    const float cqb0 = muv.x * inv0 * inv0,          cqb1 = muv.y * inv1 * inv1;
    const float cqc0 = -lsv.x - HALF_LN2PI - 0.5f * muv.x * muv.x * inv0 * inv0 + tbv.x;
    const float cqc1 = -lsv.y - HALF_LN2PI - 0.5f * muv.y * muv.y * inv1 * inv1 + tbv.y;
    const float tbb0 = tbv.x - wv.x * tbv.x,         tbb1 = tbv.y - wv.y * tbv.y;
    float w8_0, w8_1;
    { float a2 = wv.x * wv.x, a4 = a2 * a2; w8_0 = a4 * a4;
      float b2 = wv.y * wv.y, b4 = b2 * b2; w8_1 = b4 * b4; }
    const float w16_0 = fminf(w8_0 * w8_0, PCLAMP), w16_1 = fminf(w8_1 * w8_1, PCLAMP);
    const float w24_0 = fminf(w16_0 * w8_0, PCLAMP), w24_1 = fminf(w16_1 * w8_1, PCLAMP);
    const float W32_0 = fminf(w16_0 * w16_0, PCLAMP), W32_1 = fminf(w16_1 * w16_1, PCLAMP);
    const float l2w0 = log2f(wv.x), l2w1 = log2f(wv.y);
    const float WEL0 = fminf(exp2f(l2w0 * 512.0f), PCLAMP);
    const float WEL1 = fminf(exp2f(l2w1 * 512.0f), PCLAMP);
    const float pY0 = fminf(exp2f(l2w0 * (float)(GW * g)), PCLAMP);
    const float pY1 = fminf(exp2f(l2w1 * (float)(GW * g)), PCLAMP);
    const float pX0 = fminf(exp2f(l2w0 * (float)(GW * (NG - 1 - g))), PCLAMP);
    const float pX1 = fminf(exp2f(l2w1 * (float)(GW * (NG - 1 - g))), PCLAMP);
    const bool th0 = (e == 0) && (g == 0);

    __syncthreads();

#define EMIT0(xv) fmaf(fmaf(cqa0, (xv), cqb0), (xv), cqc0)
#define EMIT1(xv) fmaf(fmaf(cqa1, (xv), cqb1), (xv), cqc1)

    // ---- Phase A: per-chunk zero-carry scans, both states ----
    float lbs0[CPT2], lbs1[CPT2];
    float AF0 = 0.f, AF1 = 0.f;
#pragma unroll
    for (int i = 0; i < CPT2; ++i) {
        const float4* q4 = (const float4*)(s_obvs + t0 + i * CL2);
        float4 va = q4[0], vb = q4[1];
        float x[CL2] = {va.x, va.y, va.z, va.w, vb.x, vb.y, vb.z, vb.w};
        float e0[CL2];
#pragma unroll
        for (int j = 0; j < CL2; ++j) { e0[j] = EMIT0(x[j]); x[j] = EMIT1(x[j]); }
        if (th0 && i == 0) { e0[0] += piv.x - tbv.x; x[0] += piv.y - tbv.y; }
#pragma unroll
        for (int j = 0; j < CL2; ++j) {
            AF0 = fmaf(wv.x, AF0, e0[j]);
            AF1 = fmaf(wv.y, AF1, x[j]);
        }
        float l0 = 0.f, l1 = 0.f;
#pragma unroll
        for (int j = CL2 - 2; j >= -1; --j) {
            l0 = fmaf(wv.x, l0 + e0[j + 1], tbb0);
            l1 = fmaf(wv.y, l1 + x[j + 1], tbb1);
        }
        lbs0[i] = l0; lbs1[i] = l1;
    }
    const float Z3_0 = lbs0[3], Z3_1 = lbs1[3];
    const float Z2_0 = fmaf(w8_0, Z3_0, lbs0[2]), Z2_1 = fmaf(w8_1, Z3_1, lbs1[2]);
    const float Z1_0 = fmaf(w8_0, Z2_0, lbs0[1]), Z1_1 = fmaf(w8_1, Z2_1, lbs1[1]);
    const float ZT0  = fmaf(w8_0, Z1_0, lbs0[0]), ZT1  = fmaf(w8_1, Z1_1, lbs1[0]);

    *(float2*)&s_PF[g][s0] = make_float2(AF0, AF1);
    *(float2*)&s_ZB[g][s0] = make_float2(ZT0, ZT1);
    __syncthreads();

    // ---- Phase B: 4-round Kogge-Stone over 16 group aggregates ----
    {
        float Wd0 = W32_0, Wd1 = W32_1;
#pragma unroll
        for (int r = 0; r < 4; ++r) {
            const int d = 1 << r;
            float2 tF = (g >= d)     ? *(const float2*)&s_PF[g - d][s0] : make_float2(0.f, 0.f);
            float2 tB = (g + d < NG) ? *(const float2*)&s_ZB[g + d][s0] : make_float2(0.f, 0.f);
            __syncthreads();
            if (g >= d) {
                s_PF[g][s0]     = fmaf(Wd0, tF.x, s_PF[g][s0]);
                s_PF[g][s0 + 1] = fmaf(Wd1, tF.y, s_PF[g][s0 + 1]);
            }
            if (g + d < NG) {
                s_ZB[g][s0]     = fmaf(Wd0, tB.x, s_ZB[g][s0]);
                s_ZB[g][s0 + 1] = fmaf(Wd1, tB.y, s_ZB[g][s0 + 1]);
            }
            Wd0 = fminf(Wd0 * Wd0, PCLAMP);
            Wd1 = fminf(Wd1 * Wd1, PCLAMP);
            __syncthreads();
        }
    }

    // ---- cross-eighth carries ----
    float Y0 = 0.f, Y1 = 0.f;
#pragma unroll
    for (int qq = 0; qq < NE - 1; ++qq)
        if (qq < e) {
            float2 L = *(const float2*)&ws[OFF_LF + (size_t)(b * NE + qq) * Sn + s0];
            Y0 = fmaf(WEL0, Y0, L.x);
            Y1 = fmaf(WEL1, Y1, L.y);
        }
    float xT = obvs[(size_t)b * Tn + Tn - 1];
    float X0 = EMIT0(xT) + (piv.x - tbv.x);
    float X1 = EMIT1(xT) + (piv.y - tbv.y);
#pragma unroll
    for (int qq = NE - 1; qq > 0; --qq)
        if (qq > e) {
            float2 L = *(const float2*)&ws[OFF_LB + (size_t)(b * NE + qq) * Sn + s0];
            X0 = fmaf(WEL0, X0, L.x);
            X1 = fmaf(WEL1, X1, L.y);
        }

    // ---- thread carries ----
    float2 Pp = (g > 0)      ? *(const float2*)&s_PF[g - 1][s0] : make_float2(0.f, 0.f);
    float2 Zn = (g < NG - 1) ? *(const float2*)&s_ZB[g + 1][s0] : make_float2(0.f, 0.f);
    float f0 = fmaf(pY0, Y0, Pp.x);
    float f1 = fmaf(pY1, Y1, Pp.y);
    const float Xth0 = fmaf(pX0, X0, Zn.x);
    const float Xth1 = fmaf(pX1, X1, Zn.y);
    float R0[CPT2], R1[CPT2];
    R0[3] = Xth0;                    R1[3] = Xth1;
    R0[2] = fmaf(w8_0,  Xth0, Z3_0); R1[2] = fmaf(w8_1,  Xth1, Z3_1);
    R0[1] = fmaf(w16_0, Xth0, Z2_0); R1[1] = fmaf(w16_1, Xth1, Z2_1);
    R0[0] = fmaf(w24_0, Xth0, Z1_0); R1[0] = fmaf(w24_1, Xth1, Z1_1);

    const size_t rowbase = (size_t)b * Tn + (size_t)e * EL;
    float* outp = out + ((rowbase + t0) << 5) + s0;

    // ---- Phase C: dual f-chains + dual bwd fills + shared LSE + float2 stores ----
#pragma unroll
    for (int i = 0; i < CPT2; ++i) {
        const float4* q4 = (const float4*)(s_obvs + t0 + i * CL2);
        float4 va = q4[0], vb = q4[1];
        float x[CL2] = {va.x, va.y, va.z, va.w, vb.x, vb.y, vb.z, vb.w};
        float e0[CL2];
#pragma unroll
        for (int j = 0; j < CL2; ++j) { e0[j] = EMIT0(x[j]); x[j] = EMIT1(x[j]); }
        if (th0 && i == 0) { e0[0] += piv.x - tbv.x; x[0] += piv.y - tbv.y; }

        float b0[CL2], b1[CL2];
        b0[CL2 - 1] = R0[i]; b1[CL2 - 1] = R1[i];
#pragma unroll
        for (int j = CL2 - 2; j >= 0; --j) {
            b0[j] = fmaf(wv.x, b0[j + 1] + e0[j + 1], tbb0);
            b1[j] = fmaf(wv.y, b1[j + 1] + x[j + 1], tbb1);
        }

#pragma unroll
        for (int j = 0; j < CL2; ++j) {
            f0 = fmaf(wv.x, f0, e0[j]);
            f1 = fmaf(wv.y, f1, x[j]);
            float v0 = f0 + b0[j];
            float v1 = f1 + b1[j];
            float sum = __expf(v0) + __expf(v1);   // v <= 0
            sum = DPP_ADD(sum, 0xB1);              // quad_perm xor1
            sum = DPP_ADD(sum, 0x4E);              // quad_perm xor2
            sum = DPP_ADD(sum, 0x141);             // row_half_mirror
            sum = DPP_ADD(sum, 0x128);             // row_ror:8
            sum = fmaxf(sum, 1.0e-35f);
            float lse = __logf(sum);
            float2 r = make_float2(fmaxf(v0 - lse, SAT), fmaxf(v1 - lse, SAT));
            *(float2*)(outp + ((size_t)(i * CL2 + j) << 5)) = r;
        }
    }
#undef EMIT0
#undef EMIT1
}

extern "C" void kernel_launch(void* const* d_in, const int* in_sizes, int n_in,
                              void* d_out, int out_size, void* d_ws, size_t ws_size,
                              hipStream_t stream)
{
    const float* obvs      = (const float*)d_in[0];
    const float* ln_pi     = (const float*)d_in[1];
    const float* trans_w   = (const float*)d_in[2];
    const float* trans_b   = (const float*)d_in[3];
    const float* mu        = (const float*)d_in[4];
    const float* log_sigma = (const float*)d_in[5];
    float* out = (float*)d_out;
    float* wsf = (float*)d_ws;    // 256 KB used

    hipLaunchKernelGGL(hmm_agg_kernel, dim3(Bn * NE), dim3(NT2), 0, stream,
                       obvs, ln_pi, trans_w, trans_b, mu, log_sigma, wsf);
    hipLaunchKernelGGL(hmm_main_kernel, dim3(Bn * NE), dim3(NT2), 0, stream,
                       obvs, ln_pi, trans_w, trans_b, mu, log_sigma, out, wsf);
}